// Round 1
// baseline (5731.108 us; speedup 1.0000x reference)
//
#include <hip/hip_runtime.h>
#include <hip/hip_bf16.h>
#include <math.h>

#define B 16
#define NTOK 4096
#define DIM 256
#define DEPTH 4
#define HEADS 8
#define DH 32
#define INNER 256
#define MLPD 1024
#define EPS 1e-5f

__device__ __forceinline__ float gelu_exact(float v) {
    return 0.5f * v * (1.f + erff(v * 0.70710678118654752440f));
}

// ---------------------------------------------------------------------------
// K1: per-batch prep: gather center token, q = sel@Wq, qk[h][c] = scale * sum_d Wk[c][h*32+d]*q[h*32+d]
// grid: B blocks, 256 threads
__global__ __launch_bounds__(256) void attn_prep(
        const float* __restrict__ x, const int* __restrict__ pidx,
        const int* __restrict__ scale,
        const float* __restrict__ Wq, const float* __restrict__ Wk,
        float* __restrict__ qk)
{
    const int b = blockIdx.x;
    const int tid = threadIdx.x;
    __shared__ float sel[DIM];
    __shared__ float qs[INNER];
    const int idx = pidx[b*2 + 0] * scale[1] + pidx[b*2 + 1];
    sel[tid] = x[(size_t)b*NTOK*DIM + (size_t)idx*DIM + tid];
    __syncthreads();
    float acc = 0.f;
    for (int c = 0; c < DIM; ++c) acc += sel[c] * Wq[c*INNER + tid];
    qs[tid] = acc;
    __syncthreads();
    const float ascale = 0.17677669529663687f; // 32^-0.5
    const int c = tid;
    #pragma unroll
    for (int h = 0; h < HEADS; ++h) {
        float s = 0.f;
        #pragma unroll
        for (int d = 0; d < DH; ++d) s += Wk[c*INNER + h*DH + d] * qs[h*DH + d];
        qk[(b*HEADS + h)*DIM + c] = s * ascale;
    }
}

// ---------------------------------------------------------------------------
// K2: dots[b,h,n] = sum_c x[b,n,c] * qk[b,h,c]
// grid: (NTOK/32, B), 256 threads
__global__ __launch_bounds__(256) void dots_kernel(
        const float* __restrict__ x, const float* __restrict__ qk,
        float* __restrict__ dots)
{
    const int b = blockIdx.y;
    const int n0 = blockIdx.x * 32;
    const int tid = threadIdx.x;
    __shared__ float xs[32][260];
    __shared__ float qs[HEADS][260];
    const float4* xg = (const float4*)(x + (size_t)b*NTOK*DIM + (size_t)n0*DIM);
    #pragma unroll
    for (int i = 0; i < 8; ++i) {
        int flat = tid + 256*i;
        int r = flat >> 6, c4 = flat & 63;
        *(float4*)&xs[r][c4*4] = xg[flat];
    }
    const float4* qg = (const float4*)(qk + (size_t)b*HEADS*DIM);
    #pragma unroll
    for (int i = 0; i < 2; ++i) {
        int flat = tid + 256*i;
        int h = flat >> 6, c4 = flat & 63;
        *(float4*)&qs[h][c4*4] = qg[flat];
    }
    __syncthreads();
    const int tok = tid >> 3, h = tid & 7;
    float acc = 0.f;
    #pragma unroll 8
    for (int i = 0; i < 64; ++i) {
        float4 xv = *(const float4*)&xs[tok][i*4];
        float4 qv = *(const float4*)&qs[h][i*4];
        acc += xv.x*qv.x + xv.y*qv.y + xv.z*qv.z + xv.w*qv.w;
    }
    dots[((size_t)(b*HEADS + h))*NTOK + n0 + tok] = acc;
}

// ---------------------------------------------------------------------------
// K3: softmax over last dim (4096), in place. grid: B*HEADS, 256 threads
__global__ __launch_bounds__(256) void softmax_kernel(float* __restrict__ dots)
{
    float* p = dots + (size_t)blockIdx.x * NTOK;
    const int tid = threadIdx.x;
    float v[16];
    float mx = -3.4e38f;
    #pragma unroll
    for (int i = 0; i < 16; ++i) { v[i] = p[tid + 256*i]; mx = fmaxf(mx, v[i]); }
    #pragma unroll
    for (int o = 32; o > 0; o >>= 1) mx = fmaxf(mx, __shfl_xor(mx, o));
    __shared__ float red[4];
    const int wave = tid >> 6;
    if ((tid & 63) == 0) red[wave] = mx;
    __syncthreads();
    mx = fmaxf(fmaxf(red[0], red[1]), fmaxf(red[2], red[3]));
    float s = 0.f;
    #pragma unroll
    for (int i = 0; i < 16; ++i) { v[i] = __expf(v[i] - mx); s += v[i]; }
    #pragma unroll
    for (int o = 32; o > 0; o >>= 1) s += __shfl_xor(s, o);
    __syncthreads();
    if ((tid & 63) == 0) red[wave] = s;
    __syncthreads();
    s = red[0] + red[1] + red[2] + red[3];
    const float inv = 1.f / s;
    #pragma unroll
    for (int i = 0; i < 16; ++i) p[tid + 256*i] = v[i] * inv;
}

// ---------------------------------------------------------------------------
__global__ void zero_kernel(float* __restrict__ p, int n)
{
    int i = blockIdx.x * blockDim.x + threadIdx.x;
    if (i < n) p[i] = 0.f;
}

// ---------------------------------------------------------------------------
// K5: xa[b,h,c] += sum_n attn[b,h,n] * x[b,n,c]   (partial over n-chunk, atomic)
// grid: (8, B), 256 threads; each block does 512 tokens
__global__ __launch_bounds__(256) void xa_kernel(
        const float* __restrict__ x, const float* __restrict__ attn,
        float* __restrict__ xa)
{
    const int b = blockIdx.y;
    const int n0 = blockIdx.x * (NTOK/8);
    const int tid = threadIdx.x;
    __shared__ float as[HEADS][NTOK/8];
    const float* ag = attn + (size_t)b*HEADS*NTOK;
    #pragma unroll
    for (int i = 0; i < 16; ++i) {
        int flat = tid + 256*i;
        int h = flat >> 9, n = flat & 511;
        as[h][n] = ag[(size_t)h*NTOK + n0 + n];
    }
    __syncthreads();
    float acc[HEADS];
    #pragma unroll
    for (int h = 0; h < HEADS; ++h) acc[h] = 0.f;
    const float* xg = x + (size_t)b*NTOK*DIM + (size_t)n0*DIM + tid;
    for (int n = 0; n < NTOK/8; ++n) {
        float xv = xg[(size_t)n*DIM];
        #pragma unroll
        for (int h = 0; h < HEADS; ++h) acc[h] += as[h][n] * xv;
    }
    #pragma unroll
    for (int h = 0; h < HEADS; ++h)
        atomicAdd(&xa[(b*HEADS + h)*DIM + tid], acc[h]);
}

// ---------------------------------------------------------------------------
// K6: vo = xa @ Wv (per-head slices), out = vo@Wo + bo, x[b,idx] += out
// grid: B, 256 threads
__global__ __launch_bounds__(256) void attn_out_kernel(
        const float* __restrict__ xa, const float* __restrict__ Wv,
        const float* __restrict__ Wo, const float* __restrict__ bo,
        const int* __restrict__ pidx, const int* __restrict__ scale,
        float* __restrict__ x)
{
    const int b = blockIdx.x;
    const int tid = threadIdx.x;
    __shared__ float xs[HEADS*DIM];
    __shared__ float vs[INNER];
    #pragma unroll
    for (int i = 0; i < 8; ++i) xs[tid + 256*i] = xa[b*HEADS*DIM + tid + 256*i];
    __syncthreads();
    const int h = tid >> 5;
    float acc = 0.f;
    for (int c = 0; c < DIM; ++c) acc += xs[h*DIM + c] * Wv[c*INNER + tid];
    vs[tid] = acc;
    __syncthreads();
    float o = bo[tid];
    for (int i = 0; i < INNER; ++i) o += vs[i] * Wo[i*DIM + tid];
    const int idx = pidx[b*2 + 0] * scale[1] + pidx[b*2 + 1];
    x[(size_t)b*NTOK*DIM + (size_t)idx*DIM + tid] += o;
}

// ---------------------------------------------------------------------------
// K7: fused FFN: x += W2^T gelu(W1^T LN(x) + b1) + b2 for a 32-token tile
// grid: B*NTOK/32, 256 threads
__global__ __launch_bounds__(256) void ffn_kernel(
        float* __restrict__ x,
        const float* __restrict__ g, const float* __restrict__ bvec,
        const float* __restrict__ W1, const float* __restrict__ b1,
        const float* __restrict__ W2, const float* __restrict__ b2)
{
    __shared__ float xs[32][260];
    __shared__ float hs[32][132];
    const int tid = threadIdx.x;
    const size_t row0 = (size_t)blockIdx.x * 32;

    {   // stage x tile
        const float4* xg = (const float4*)(x + row0*DIM);
        #pragma unroll
        for (int i = 0; i < 8; ++i) {
            int flat = tid + 256*i;
            int r = flat >> 6, c4 = flat & 63;
            *(float4*)&xs[r][c4*4] = xg[flat];
        }
    }
    __syncthreads();
    {   // layernorm in place (8 threads per row)
        const int r = tid >> 3, p = tid & 7;
        float s = 0.f, s2 = 0.f;
        #pragma unroll
        for (int i = 0; i < 8; ++i) {
            float4 v = *(const float4*)&xs[r][(p + 8*i)*4];
            s  += v.x + v.y + v.z + v.w;
            s2 += v.x*v.x + v.y*v.y + v.z*v.z + v.w*v.w;
        }
        #pragma unroll
        for (int o = 1; o < 8; o <<= 1) { s += __shfl_xor(s, o); s2 += __shfl_xor(s2, o); }
        const float mean = s * (1.f/DIM);
        const float rstd = rsqrtf(s2*(1.f/DIM) - mean*mean + EPS);
        #pragma unroll
        for (int i = 0; i < 8; ++i) {
            const int c4 = (p + 8*i)*4;
            float4 v = *(const float4*)&xs[r][c4];
            const float4 gg = *(const float4*)&g[c4];
            const float4 bb = *(const float4*)&bvec[c4];
            v.x = (v.x - mean)*rstd*gg.x + bb.x;
            v.y = (v.y - mean)*rstd*gg.y + bb.y;
            v.z = (v.z - mean)*rstd*gg.z + bb.z;
            v.w = (v.w - mean)*rstd*gg.w + bb.w;
            *(float4*)&xs[r][c4] = v;
        }
    }
    __syncthreads();

    const int tc = tid & 31;
    const int tr4 = (tid >> 5) * 4;
    float acc2[4][8];
    #pragma unroll
    for (int rr = 0; rr < 4; ++rr)
        #pragma unroll
        for (int cc = 0; cc < 8; ++cc) acc2[rr][cc] = 0.f;

    for (int j0 = 0; j0 < MLPD; j0 += 128) {
        // ---- GEMM1: hs[32][128] = gelu(xs @ W1[:, j0:j0+128] + b1)
        float acc1[4][4];
        #pragma unroll
        for (int rr = 0; rr < 4; ++rr)
            #pragma unroll
            for (int cc = 0; cc < 4; ++cc) acc1[rr][cc] = 0.f;
        const float* w1p = W1 + j0 + tc*4;
        #pragma unroll 4
        for (int c = 0; c < DIM; ++c) {
            const float4 w = *(const float4*)(w1p + (size_t)c*MLPD);
            float a[4];
            #pragma unroll
            for (int rr = 0; rr < 4; ++rr) a[rr] = xs[tr4+rr][c];
            #pragma unroll
            for (int rr = 0; rr < 4; ++rr) {
                acc1[rr][0] += a[rr]*w.x;
                acc1[rr][1] += a[rr]*w.y;
                acc1[rr][2] += a[rr]*w.z;
                acc1[rr][3] += a[rr]*w.w;
            }
        }
        const float4 b1v = *(const float4*)&b1[j0 + tc*4];
        #pragma unroll
        for (int rr = 0; rr < 4; ++rr) {
            float4 hv;
            hv.x = gelu_exact(acc1[rr][0] + b1v.x);
            hv.y = gelu_exact(acc1[rr][1] + b1v.y);
            hv.z = gelu_exact(acc1[rr][2] + b1v.z);
            hv.w = gelu_exact(acc1[rr][3] + b1v.w);
            *(float4*)&hs[tr4+rr][tc*4] = hv;
        }
        __syncthreads();
        // ---- GEMM2: acc2 += hs @ W2[j0:j0+128, :]
        const float* w2p = W2 + (size_t)j0*DIM + tc*8;
        #pragma unroll 2
        for (int k = 0; k < 128; ++k) {
            const float4 wa = *(const float4*)(w2p + (size_t)k*DIM);
            const float4 wb = *(const float4*)(w2p + (size_t)k*DIM + 4);
            float a[4];
            #pragma unroll
            for (int rr = 0; rr < 4; ++rr) a[rr] = hs[tr4+rr][k];
            #pragma unroll
            for (int rr = 0; rr < 4; ++rr) {
                acc2[rr][0] += a[rr]*wa.x;
                acc2[rr][1] += a[rr]*wa.y;
                acc2[rr][2] += a[rr]*wa.z;
                acc2[rr][3] += a[rr]*wa.w;
                acc2[rr][4] += a[rr]*wb.x;
                acc2[rr][5] += a[rr]*wb.y;
                acc2[rr][6] += a[rr]*wb.z;
                acc2[rr][7] += a[rr]*wb.w;
            }
        }
        __syncthreads();
    }
    // ---- epilogue: += b2 + residual, store
    const float4 b2a = *(const float4*)&b2[tc*8];
    const float4 b2b = *(const float4*)&b2[tc*8 + 4];
    #pragma unroll
    for (int rr = 0; rr < 4; ++rr) {
        float* xp = x + (row0 + tr4 + rr)*DIM + tc*8;
        float4 r0 = *(const float4*)xp;
        float4 r1 = *(const float4*)(xp + 4);
        r0.x += acc2[rr][0] + b2a.x;
        r0.y += acc2[rr][1] + b2a.y;
        r0.z += acc2[rr][2] + b2a.z;
        r0.w += acc2[rr][3] + b2a.w;
        r1.x += acc2[rr][4] + b2b.x;
        r1.y += acc2[rr][5] + b2b.y;
        r1.z += acc2[rr][6] + b2b.z;
        r1.w += acc2[rr][7] + b2b.w;
        *(float4*)xp = r0;
        *(float4*)(xp + 4) = r1;
    }
}

// ---------------------------------------------------------------------------
// K8: final layernorm, x -> out (safe in place: row held in registers)
// grid: B*NTOK/32, 256 threads (8 per row)
__global__ __launch_bounds__(256) void final_ln_kernel(
        const float* __restrict__ x, const float* __restrict__ g,
        const float* __restrict__ bvec, float* __restrict__ out)
{
    const int tid = threadIdx.x;
    const size_t row = (size_t)blockIdx.x*32 + (tid >> 3);
    const int p = tid & 7;
    const float4* xr = (const float4*)(x + row*DIM);
    float4 v[8];
    float s = 0.f, s2 = 0.f;
    #pragma unroll
    for (int i = 0; i < 8; ++i) {
        v[i] = xr[p + 8*i];
        s  += v[i].x + v[i].y + v[i].z + v[i].w;
        s2 += v[i].x*v[i].x + v[i].y*v[i].y + v[i].z*v[i].z + v[i].w*v[i].w;
    }
    #pragma unroll
    for (int o = 1; o < 8; o <<= 1) { s += __shfl_xor(s, o); s2 += __shfl_xor(s2, o); }
    const float mean = s * (1.f/DIM);
    const float rstd = rsqrtf(s2*(1.f/DIM) - mean*mean + EPS);
    float4* og = (float4*)(out + row*DIM);
    #pragma unroll
    for (int i = 0; i < 8; ++i) {
        const int c4 = (p + 8*i)*4;
        const float4 gg = *(const float4*)&g[c4];
        const float4 bb = *(const float4*)&bvec[c4];
        float4 o_;
        o_.x = (v[i].x - mean)*rstd*gg.x + bb.x;
        o_.y = (v[i].y - mean)*rstd*gg.y + bb.y;
        o_.z = (v[i].z - mean)*rstd*gg.z + bb.z;
        o_.w = (v[i].w - mean)*rstd*gg.w + bb.w;
        og[p + 8*i] = o_;
    }
}

// ---------------------------------------------------------------------------
extern "C" void kernel_launch(void* const* d_in, const int* in_sizes, int n_in,
                              void* d_out, int out_size, void* d_ws, size_t ws_size,
                              hipStream_t stream)
{
    const float* x_in  = (const float*)d_in[0];
    const int*   pidx  = (const int*)d_in[1];
    // d_in[2] = data, unused
    const int*   scale = (const int*)d_in[3];
    const float* Wq    = (const float*)d_in[4];
    const float* Wk    = (const float*)d_in[5];
    const float* Wv    = (const float*)d_in[6];
    const float* Wo    = (const float*)d_in[7];
    const float* bo    = (const float*)d_in[8];
    const float* ln_g  = (const float*)d_in[9];
    const float* ln_b  = (const float*)d_in[10];
    const float* W1    = (const float*)d_in[11];
    const float* b1    = (const float*)d_in[12];
    const float* W2    = (const float*)d_in[13];
    const float* b2    = (const float*)d_in[14];
    const float* lnf_g = (const float*)d_in[15];
    const float* lnf_b = (const float*)d_in[16];

    // x lives in d_out (exactly B*NTOK*DIM f32); ws only holds small buffers.
    float* xbuf = (float*)d_out;
    float* qk   = (float*)d_ws;                       // B*HEADS*DIM
    float* dots = qk + (size_t)B*HEADS*DIM;           // B*HEADS*NTOK
    float* xa   = dots + (size_t)B*HEADS*NTOK;        // B*HEADS*DIM

    hipMemcpyAsync(xbuf, x_in, (size_t)B*NTOK*DIM*sizeof(float),
                   hipMemcpyDeviceToDevice, stream);

    for (int l = 0; l < DEPTH; ++l) {
        attn_prep<<<B, 256, 0, stream>>>(
            xbuf, pidx, scale,
            Wq + (size_t)l*DIM*INNER, Wk + (size_t)l*DIM*INNER, qk);
        dots_kernel<<<dim3(NTOK/32, B), 256, 0, stream>>>(xbuf, qk, dots);
        softmax_kernel<<<B*HEADS, 256, 0, stream>>>(dots);
        zero_kernel<<<(B*HEADS*DIM + 255)/256, 256, 0, stream>>>(xa, B*HEADS*DIM);
        xa_kernel<<<dim3(8, B), 256, 0, stream>>>(xbuf, dots, xa);
        attn_out_kernel<<<B, 256, 0, stream>>>(
            xa, Wv + (size_t)l*DIM*INNER, Wo + (size_t)l*INNER*DIM,
            bo + (size_t)l*DIM, pidx, scale, xbuf);
        ffn_kernel<<<(B*NTOK)/32, 256, 0, stream>>>(
            xbuf, ln_g + (size_t)l*DIM, ln_b + (size_t)l*DIM,
            W1 + (size_t)l*DIM*MLPD, b1 + (size_t)l*MLPD,
            W2 + (size_t)l*MLPD*DIM, b2 + (size_t)l*DIM);
    }
    final_ln_kernel<<<(B*NTOK)/32, 256, 0, stream>>>(xbuf, lnf_g, lnf_b, xbuf);
}

// Round 2
// 1697.307 us; speedup vs baseline: 3.3766x; 3.3766x over previous
//
#include <hip/hip_runtime.h>
#include <hip/hip_bf16.h>
#include <math.h>

#define B 16
#define NTOK 4096
#define DIM 256
#define DEPTH 4
#define HEADS 8
#define DH 32
#define INNER 256
#define MLPD 1024
#define EPS 1e-5f

typedef _Float16 half8 __attribute__((ext_vector_type(8)));
typedef _Float16 half4v __attribute__((ext_vector_type(4)));
typedef float f32x4 __attribute__((ext_vector_type(4)));

__device__ __forceinline__ float gelu_exact(float v) {
    return 0.5f * v * (1.f + erff(v * 0.70710678118654752440f));
}

// ---------------------------------------------------------------------------
// Pack fp32 weight [K][C] into fp16 MFMA-fragment-major layout:
// out[ (c/16) * (K/32) + (k/32) ][ lane ][ 8 ]  where lane supplies
// row c%16 = lane&15, k-block = (lane>>4)*8. One layer per blockIdx.z.
__global__ __launch_bounds__(256) void pack_w(
        const float* __restrict__ in, _Float16* __restrict__ out, int K, int C)
{
    in  += (size_t)blockIdx.z * K * C;
    out += (size_t)blockIdx.z * K * C;
    __shared__ float t[32][65];
    const int tid = threadIdx.x;
    const int c0 = blockIdx.x * 64, k0 = blockIdx.y * 32;
    #pragma unroll
    for (int i = 0; i < 8; ++i) {
        int flat = tid + 256*i;
        int kk = flat >> 6, ccl = flat & 63;
        t[kk][ccl] = in[(size_t)(k0 + kk)*C + c0 + ccl];
    }
    __syncthreads();
    const int lane = tid & 63, ctl = tid >> 6;
    const int ccl = ctl*16 + (lane & 15);
    const int kb = (lane >> 4) * 8;
    half8 v;
    #pragma unroll
    for (int i = 0; i < 8; ++i) v[i] = (_Float16)t[kb + i][ccl];
    size_t off = ((size_t)((c0 >> 4) + ctl) * (K/32) + (k0 >> 5)) * 64 + lane;
    *((half8*)out + off) = v;
}

// ---------------------------------------------------------------------------
// K1: per-batch prep: gather center token, q = sel@Wq, qk[h][c]
__global__ __launch_bounds__(256) void attn_prep(
        const float* __restrict__ x, const int* __restrict__ pidx,
        const int* __restrict__ scale,
        const float* __restrict__ Wq, const float* __restrict__ Wk,
        float* __restrict__ qk)
{
    const int b = blockIdx.x;
    const int tid = threadIdx.x;
    __shared__ float sel[DIM];
    __shared__ float qs[INNER];
    const int idx = pidx[b*2 + 0] * scale[1] + pidx[b*2 + 1];
    sel[tid] = x[(size_t)b*NTOK*DIM + (size_t)idx*DIM + tid];
    __syncthreads();
    float acc = 0.f;
    for (int c = 0; c < DIM; ++c) acc += sel[c] * Wq[c*INNER + tid];
    qs[tid] = acc;
    __syncthreads();
    const float ascale = 0.17677669529663687f; // 32^-0.5
    const int c = tid;
    #pragma unroll
    for (int h = 0; h < HEADS; ++h) {
        float s = 0.f;
        #pragma unroll
        for (int d = 0; d < DH; ++d) s += Wk[c*INNER + h*DH + d] * qs[h*DH + d];
        qk[(b*HEADS + h)*DIM + c] = s * ascale;
    }
}

// ---------------------------------------------------------------------------
// K2: dots[b,h,n] = sum_c x[b,n,c] * qk[b,h,c]
__global__ __launch_bounds__(256) void dots_kernel(
        const float* __restrict__ x, const float* __restrict__ qk,
        float* __restrict__ dots)
{
    const int b = blockIdx.y;
    const int n0 = blockIdx.x * 32;
    const int tid = threadIdx.x;
    __shared__ float xs[32][260];
    __shared__ float qs[HEADS][260];
    const float4* xg = (const float4*)(x + (size_t)b*NTOK*DIM + (size_t)n0*DIM);
    #pragma unroll
    for (int i = 0; i < 8; ++i) {
        int flat = tid + 256*i;
        int r = flat >> 6, c4 = flat & 63;
        *(float4*)&xs[r][c4*4] = xg[flat];
    }
    const float4* qg = (const float4*)(qk + (size_t)b*HEADS*DIM);
    #pragma unroll
    for (int i = 0; i < 2; ++i) {
        int flat = tid + 256*i;
        int h = flat >> 6, c4 = flat & 63;
        *(float4*)&qs[h][c4*4] = qg[flat];
    }
    __syncthreads();
    const int tok = tid >> 3, h = tid & 7;
    float acc = 0.f;
    #pragma unroll 8
    for (int i = 0; i < 64; ++i) {
        float4 xv = *(const float4*)&xs[tok][i*4];
        float4 qv = *(const float4*)&qs[h][i*4];
        acc += xv.x*qv.x + xv.y*qv.y + xv.z*qv.z + xv.w*qv.w;
    }
    dots[((size_t)(b*HEADS + h))*NTOK + n0 + tok] = acc;
}

// ---------------------------------------------------------------------------
// K3: softmax over last dim (4096), in place.
__global__ __launch_bounds__(256) void softmax_kernel(float* __restrict__ dots)
{
    float* p = dots + (size_t)blockIdx.x * NTOK;
    const int tid = threadIdx.x;
    float v[16];
    float mx = -3.4e38f;
    #pragma unroll
    for (int i = 0; i < 16; ++i) { v[i] = p[tid + 256*i]; mx = fmaxf(mx, v[i]); }
    #pragma unroll
    for (int o = 32; o > 0; o >>= 1) mx = fmaxf(mx, __shfl_xor(mx, o));
    __shared__ float red[4];
    const int wave = tid >> 6;
    if ((tid & 63) == 0) red[wave] = mx;
    __syncthreads();
    mx = fmaxf(fmaxf(red[0], red[1]), fmaxf(red[2], red[3]));
    float s = 0.f;
    #pragma unroll
    for (int i = 0; i < 16; ++i) { v[i] = __expf(v[i] - mx); s += v[i]; }
    #pragma unroll
    for (int o = 32; o > 0; o >>= 1) s += __shfl_xor(s, o);
    __syncthreads();
    if ((tid & 63) == 0) red[wave] = s;
    __syncthreads();
    s = red[0] + red[1] + red[2] + red[3];
    const float inv = 1.f / s;
    #pragma unroll
    for (int i = 0; i < 16; ++i) p[tid + 256*i] = v[i] * inv;
}

// ---------------------------------------------------------------------------
__global__ void zero_kernel(float* __restrict__ p, int n)
{
    int i = blockIdx.x * blockDim.x + threadIdx.x;
    if (i < n) p[i] = 0.f;
}

// ---------------------------------------------------------------------------
// K5: xa[b,h,c] += sum_n attn[b,h,n] * x[b,n,c]
__global__ __launch_bounds__(256) void xa_kernel(
        const float* __restrict__ x, const float* __restrict__ attn,
        float* __restrict__ xa)
{
    const int b = blockIdx.y;
    const int n0 = blockIdx.x * (NTOK/8);
    const int tid = threadIdx.x;
    __shared__ float as[HEADS][NTOK/8];
    const float* ag = attn + (size_t)b*HEADS*NTOK;
    #pragma unroll
    for (int i = 0; i < 16; ++i) {
        int flat = tid + 256*i;
        int h = flat >> 9, n = flat & 511;
        as[h][n] = ag[(size_t)h*NTOK + n0 + n];
    }
    __syncthreads();
    float acc[HEADS];
    #pragma unroll
    for (int h = 0; h < HEADS; ++h) acc[h] = 0.f;
    const float* xg = x + (size_t)b*NTOK*DIM + (size_t)n0*DIM + tid;
    for (int n = 0; n < NTOK/8; ++n) {
        float xv = xg[(size_t)n*DIM];
        #pragma unroll
        for (int h = 0; h < HEADS; ++h) acc[h] += as[h][n] * xv;
    }
    #pragma unroll
    for (int h = 0; h < HEADS; ++h)
        atomicAdd(&xa[(b*HEADS + h)*DIM + tid], acc[h]);
}

// ---------------------------------------------------------------------------
// K6: vo = xa @ Wv per head, out = vo@Wo + bo, x[b,idx] += out
__global__ __launch_bounds__(256) void attn_out_kernel(
        const float* __restrict__ xa, const float* __restrict__ Wv,
        const float* __restrict__ Wo, const float* __restrict__ bo,
        const int* __restrict__ pidx, const int* __restrict__ scale,
        float* __restrict__ x)
{
    const int b = blockIdx.x;
    const int tid = threadIdx.x;
    __shared__ float xs[HEADS*DIM];
    __shared__ float vs[INNER];
    #pragma unroll
    for (int i = 0; i < 8; ++i) xs[tid + 256*i] = xa[b*HEADS*DIM + tid + 256*i];
    __syncthreads();
    const int h = tid >> 5;
    float acc = 0.f;
    for (int c = 0; c < DIM; ++c) acc += xs[h*DIM + c] * Wv[c*INNER + tid];
    vs[tid] = acc;
    __syncthreads();
    float o = bo[tid];
    for (int i = 0; i < INNER; ++i) o += vs[i] * Wo[i*DIM + tid];
    const int idx = pidx[b*2 + 0] * scale[1] + pidx[b*2 + 1];
    x[(size_t)b*NTOK*DIM + (size_t)idx*DIM + tid] += o;
}

// ---------------------------------------------------------------------------
// K7: fused FFN with fp16 MFMA. 64-token tile, 4 waves.
// Both GEMMs operand-swapped: D = W^T_tile (A) x X^T (B) so GELU output packs
// into contiguous ds_write_b64 and the epilogue is a contiguous float4/lane.
// LDS tiles XOR-swizzled (byte ^= (row&7)<<4) to kill the stride-512B
// 16-way bank conflict on ds_read_b128.
__global__ __launch_bounds__(256) void ffn_mfma(
        float* __restrict__ x,
        const float* __restrict__ g, const float* __restrict__ bvec,
        const _Float16* __restrict__ W1F, const float* __restrict__ b1,
        const _Float16* __restrict__ W2F, const float* __restrict__ b2)
{
    __shared__ _Float16 xs[64*256];   // [t][k], swizzled
    __shared__ _Float16 hsT[64*256];  // [t][chunk-c], swizzled
    const int tid = threadIdx.x;
    const size_t row0 = (size_t)blockIdx.x * 64;

    // ---- phase 1: LN (fp32) -> fp16 -> xs
    {
        const int r = tid >> 2, p = tid & 3;
        const float4* xg = (const float4*)(x + (row0 + r)*DIM) + p*16;
        float4 v[16];
        float s = 0.f, s2 = 0.f;
        #pragma unroll
        for (int i = 0; i < 16; ++i) {
            v[i] = xg[i];
            s  += v[i].x + v[i].y + v[i].z + v[i].w;
            s2 += v[i].x*v[i].x + v[i].y*v[i].y + v[i].z*v[i].z + v[i].w*v[i].w;
        }
        s  += __shfl_xor(s, 1);  s  += __shfl_xor(s, 2);
        s2 += __shfl_xor(s2, 1); s2 += __shfl_xor(s2, 2);
        const float mean = s * (1.f/DIM);
        const float rstd = rsqrtf(s2*(1.f/DIM) - mean*mean + EPS);
        #pragma unroll
        for (int q = 0; q < 8; ++q) {
            const int c8 = p*64 + q*8;
            const float4 ga = *(const float4*)&g[c8];
            const float4 gb = *(const float4*)&g[c8+4];
            const float4 ba = *(const float4*)&bvec[c8];
            const float4 bb = *(const float4*)&bvec[c8+4];
            const float4 a = v[2*q], d = v[2*q+1];
            half8 hh;
            hh[0] = (_Float16)((a.x-mean)*rstd*ga.x + ba.x);
            hh[1] = (_Float16)((a.y-mean)*rstd*ga.y + ba.y);
            hh[2] = (_Float16)((a.z-mean)*rstd*ga.z + ba.z);
            hh[3] = (_Float16)((a.w-mean)*rstd*ga.w + ba.w);
            hh[4] = (_Float16)((d.x-mean)*rstd*gb.x + bb.x);
            hh[5] = (_Float16)((d.y-mean)*rstd*gb.y + bb.y);
            hh[6] = (_Float16)((d.z-mean)*rstd*gb.z + bb.z);
            hh[7] = (_Float16)((d.w-mean)*rstd*gb.w + bb.w);
            int byte = r*512 + c8*2;
            byte ^= (r & 7) << 4;
            *(half8*)((char*)xs + byte) = hh;
        }
    }
    __syncthreads();

    const int wave = tid >> 6, lane = tid & 63;
    const int lr = lane & 15, lhi = lane >> 4;

    f32x4 acc2[4][4];
    #pragma unroll
    for (int m = 0; m < 4; ++m)
        #pragma unroll
        for (int n = 0; n < 4; ++n) acc2[m][n] = (f32x4)0.f;

    for (int cc = 0; cc < 4; ++cc) {
        // ---- GEMM1: acc1 = W1^T-slice x X^T  (c-rows x 64 tokens)
        f32x4 acc1[4][4];
        #pragma unroll
        for (int m = 0; m < 4; ++m)
            #pragma unroll
            for (int n = 0; n < 4; ++n) acc1[m][n] = (f32x4)0.f;
        #pragma unroll 2
        for (int ks = 0; ks < 8; ++ks) {
            half8 a[4], bf[4];
            #pragma unroll
            for (int m = 0; m < 4; ++m) {
                const int ctile = cc*16 + wave*4 + m;
                a[m] = *((const half8*)W1F + (size_t)(ctile*8 + ks)*64 + lane);
            }
            #pragma unroll
            for (int n = 0; n < 4; ++n) {
                int byte = (n*16 + lr)*512 + (ks*32 + lhi*8)*2;
                byte ^= (lr & 7) << 4;
                bf[n] = *(const half8*)((const char*)xs + byte);
            }
            #pragma unroll
            for (int m = 0; m < 4; ++m)
                #pragma unroll
                for (int n = 0; n < 4; ++n)
                    acc1[m][n] = __builtin_amdgcn_mfma_f32_16x16x32_f16(
                        a[m], bf[n], acc1[m][n], 0, 0, 0);
        }
        __syncthreads();  // prev chunk's GEMM2 done reading hsT
        // ---- bias + GELU + fp16 -> hsT
        #pragma unroll
        for (int m = 0; m < 4; ++m) {
            const int cbase = cc*256 + wave*64 + m*16 + lhi*4;
            const f32x4 b1v = *(const f32x4*)(b1 + cbase);
            #pragma unroll
            for (int n = 0; n < 4; ++n) {
                const int t = n*16 + lr;
                half4v hv;
                hv[0] = (_Float16)gelu_exact(acc1[m][n][0] + b1v[0]);
                hv[1] = (_Float16)gelu_exact(acc1[m][n][1] + b1v[1]);
                hv[2] = (_Float16)gelu_exact(acc1[m][n][2] + b1v[2]);
                hv[3] = (_Float16)gelu_exact(acc1[m][n][3] + b1v[3]);
                int byte = t*512 + (wave*64 + m*16 + lhi*4)*2;
                byte ^= (t & 7) << 4;
                *(half4v*)((char*)hsT + byte) = hv;
            }
        }
        __syncthreads();  // hsT ready
        // ---- GEMM2: acc2 += W2^T-slice x H^T
        #pragma unroll 2
        for (int ks = 0; ks < 8; ++ks) {
            half8 a[4], bf[4];
            #pragma unroll
            for (int m = 0; m < 4; ++m) {
                const int ctile = wave*4 + m;
                a[m] = *((const half8*)W2F + (size_t)(ctile*32 + cc*8 + ks)*64 + lane);
            }
            #pragma unroll
            for (int n = 0; n < 4; ++n) {
                int byte = (n*16 + lr)*512 + (ks*32 + lhi*8)*2;
                byte ^= (lr & 7) << 4;
                bf[n] = *(const half8*)((const char*)hsT + byte);
            }
            #pragma unroll
            for (int m = 0; m < 4; ++m)
                #pragma unroll
                for (int n = 0; n < 4; ++n)
                    acc2[m][n] = __builtin_amdgcn_mfma_f32_16x16x32_f16(
                        a[m], bf[n], acc2[m][n], 0, 0, 0);
        }
    }
    // ---- epilogue: Y^T + b2 + residual -> x
    #pragma unroll
    for (int m = 0; m < 4; ++m) {
        const int c0 = wave*64 + m*16 + lhi*4;
        const f32x4 b2v = *(const f32x4*)(b2 + c0);
        #pragma unroll
        for (int n = 0; n < 4; ++n) {
            const int t = n*16 + lr;
            float* xp = x + (row0 + t)*DIM + c0;
            float4 r = *(const float4*)xp;
            r.x += acc2[m][n][0] + b2v[0];
            r.y += acc2[m][n][1] + b2v[1];
            r.z += acc2[m][n][2] + b2v[2];
            r.w += acc2[m][n][3] + b2v[3];
            *(float4*)xp = r;
        }
    }
}

// ---------------------------------------------------------------------------
// K8: final layernorm
__global__ __launch_bounds__(256) void final_ln_kernel(
        const float* __restrict__ x, const float* __restrict__ g,
        const float* __restrict__ bvec, float* __restrict__ out)
{
    const int tid = threadIdx.x;
    const size_t row = (size_t)blockIdx.x*32 + (tid >> 3);
    const int p = tid & 7;
    const float4* xr = (const float4*)(x + row*DIM);
    float4 v[8];
    float s = 0.f, s2 = 0.f;
    #pragma unroll
    for (int i = 0; i < 8; ++i) {
        v[i] = xr[p + 8*i];
        s  += v[i].x + v[i].y + v[i].z + v[i].w;
        s2 += v[i].x*v[i].x + v[i].y*v[i].y + v[i].z*v[i].z + v[i].w*v[i].w;
    }
    #pragma unroll
    for (int o = 1; o < 8; o <<= 1) { s += __shfl_xor(s, o); s2 += __shfl_xor(s2, o); }
    const float mean = s * (1.f/DIM);
    const float rstd = rsqrtf(s2*(1.f/DIM) - mean*mean + EPS);
    float4* og = (float4*)(out + row*DIM);
    #pragma unroll
    for (int i = 0; i < 8; ++i) {
        const int c4 = (p + 8*i)*4;
        const float4 gg = *(const float4*)&g[c4];
        const float4 bb = *(const float4*)&bvec[c4];
        float4 o_;
        o_.x = (v[i].x - mean)*rstd*gg.x + bb.x;
        o_.y = (v[i].y - mean)*rstd*gg.y + bb.y;
        o_.z = (v[i].z - mean)*rstd*gg.z + bb.z;
        o_.w = (v[i].w - mean)*rstd*gg.w + bb.w;
        og[p + 8*i] = o_;
    }
}

// ---------------------------------------------------------------------------
extern "C" void kernel_launch(void* const* d_in, const int* in_sizes, int n_in,
                              void* d_out, int out_size, void* d_ws, size_t ws_size,
                              hipStream_t stream)
{
    const float* x_in  = (const float*)d_in[0];
    const int*   pidx  = (const int*)d_in[1];
    const int*   scale = (const int*)d_in[3];
    const float* Wq    = (const float*)d_in[4];
    const float* Wk    = (const float*)d_in[5];
    const float* Wv    = (const float*)d_in[6];
    const float* Wo    = (const float*)d_in[7];
    const float* bo    = (const float*)d_in[8];
    const float* ln_g  = (const float*)d_in[9];
    const float* ln_b  = (const float*)d_in[10];
    const float* W1    = (const float*)d_in[11];
    const float* b1    = (const float*)d_in[12];
    const float* W2    = (const float*)d_in[13];
    const float* b2    = (const float*)d_in[14];
    const float* lnf_g = (const float*)d_in[15];
    const float* lnf_b = (const float*)d_in[16];

    float* xbuf = (float*)d_out;                      // x lives in d_out
    float* qk   = (float*)d_ws;                       // B*H*DIM f32
    float* dots = qk + (size_t)B*HEADS*DIM;           // B*H*NTOK f32
    float* xa   = dots + (size_t)B*HEADS*NTOK;        // B*H*DIM f32
    _Float16* W1F = (_Float16*)(xa + (size_t)B*HEADS*DIM);          // DEPTH*DIM*MLPD f16
    _Float16* W2F = W1F + (size_t)DEPTH*DIM*MLPD;                   // DEPTH*MLPD*DIM f16

    // one-time (per launch) weight pack to fp16 fragment layout
    pack_w<<<dim3(MLPD/64, DIM/32, DEPTH), 256, 0, stream>>>(W1, W1F, DIM, MLPD);
    pack_w<<<dim3(DIM/64, MLPD/32, DEPTH), 256, 0, stream>>>(W2, W2F, MLPD, DIM);

    hipMemcpyAsync(xbuf, x_in, (size_t)B*NTOK*DIM*sizeof(float),
                   hipMemcpyDeviceToDevice, stream);

    for (int l = 0; l < DEPTH; ++l) {
        attn_prep<<<B, 256, 0, stream>>>(
            xbuf, pidx, scale,
            Wq + (size_t)l*DIM*INNER, Wk + (size_t)l*DIM*INNER, qk);
        dots_kernel<<<dim3(NTOK/32, B), 256, 0, stream>>>(xbuf, qk, dots);
        softmax_kernel<<<B*HEADS, 256, 0, stream>>>(dots);
        zero_kernel<<<(B*HEADS*DIM + 255)/256, 256, 0, stream>>>(xa, B*HEADS*DIM);
        xa_kernel<<<dim3(8, B), 256, 0, stream>>>(xbuf, dots, xa);
        attn_out_kernel<<<B, 256, 0, stream>>>(
            xa, Wv + (size_t)l*DIM*INNER, Wo + (size_t)l*INNER*DIM,
            bo + (size_t)l*DIM, pidx, scale, xbuf);
        ffn_mfma<<<(B*NTOK)/64, 256, 0, stream>>>(
            xbuf, ln_g + (size_t)l*DIM, ln_b + (size_t)l*DIM,
            W1F + (size_t)l*DIM*MLPD, b1 + (size_t)l*MLPD,
            W2F + (size_t)l*MLPD*DIM, b2 + (size_t)l*DIM);
    }
    final_ln_kernel<<<(B*NTOK)/32, 256, 0, stream>>>(xbuf, lnf_g, lnf_b, xbuf);
}

// Round 3
// 1297.539 us; speedup vs baseline: 4.4169x; 1.3081x over previous
//
#include <hip/hip_runtime.h>
#include <hip/hip_bf16.h>
#include <math.h>

#define B 16
#define NTOK 4096
#define DIM 256
#define DEPTH 4
#define HEADS 8
#define DH 32
#define INNER 256
#define MLPD 1024
#define EPS 1e-5f

typedef _Float16 half8 __attribute__((ext_vector_type(8)));
typedef _Float16 half4v __attribute__((ext_vector_type(4)));
typedef float f32x4 __attribute__((ext_vector_type(4)));

// gelu(v) = 0.5 v (1 + erf(v/sqrt2)); erf via Abramowitz-Stegun 7.1.26,
// |err| < 1.5e-7 absolute. ~13 VALU ops (1 v_exp, 1 v_rcp) vs erff's ~35+.
__device__ __forceinline__ float gelu_fast(float v) {
    const float z = fabsf(v) * 0.70710678118654752440f;
    const float t = __builtin_amdgcn_rcpf(1.f + 0.3275911f * z);
    const float poly = t*(0.254829592f + t*(-0.284496736f +
                      t*(1.421413741f + t*(-1.453152027f + t*1.061405429f))));
    const float e = __expf(-z*z);
    const float erfv = copysignf(1.f - poly * e, v);
    return 0.5f * v * (1.f + erfv);
}

// ---------------------------------------------------------------------------
// Pack fp32 weight [K][C] into fp16 MFMA-fragment-major layout.
__global__ __launch_bounds__(256) void pack_w(
        const float* __restrict__ in, _Float16* __restrict__ out, int K, int C)
{
    in  += (size_t)blockIdx.z * K * C;
    out += (size_t)blockIdx.z * K * C;
    __shared__ float t[32][65];
    const int tid = threadIdx.x;
    const int c0 = blockIdx.x * 64, k0 = blockIdx.y * 32;
    #pragma unroll
    for (int i = 0; i < 8; ++i) {
        int flat = tid + 256*i;
        int kk = flat >> 6, ccl = flat & 63;
        t[kk][ccl] = in[(size_t)(k0 + kk)*C + c0 + ccl];
    }
    __syncthreads();
    const int lane = tid & 63, ctl = tid >> 6;
    const int ccl = ctl*16 + (lane & 15);
    const int kb = (lane >> 4) * 8;
    half8 v;
    #pragma unroll
    for (int i = 0; i < 8; ++i) v[i] = (_Float16)t[kb + i][ccl];
    size_t off = ((size_t)((c0 >> 4) + ctl) * (K/32) + (k0 >> 5)) * 64 + lane;
    *((half8*)out + off) = v;
}

// ---------------------------------------------------------------------------
// K1: gather center token, q = sel@Wq -> qbuf[b][256]
__global__ __launch_bounds__(256) void attn_prep(
        const float* __restrict__ x, const int* __restrict__ pidx,
        const int* __restrict__ scale,
        const float* __restrict__ Wq, float* __restrict__ qbuf)
{
    const int b = blockIdx.x;
    const int tid = threadIdx.x;
    __shared__ float sel[DIM];
    const int idx = pidx[b*2 + 0] * scale[1] + pidx[b*2 + 1];
    sel[tid] = x[(size_t)b*NTOK*DIM + (size_t)idx*DIM + tid];
    __syncthreads();
    float acc = 0.f;
    #pragma unroll 4
    for (int c = 0; c < DIM; ++c) acc += sel[c] * Wq[c*INNER + tid];
    qbuf[b*DIM + tid] = acc;
}

// ---------------------------------------------------------------------------
// K1b: qk[b][h][c] = ascale * sum_d Wk[c][h*32+d] * q[b][h*32+d]
// One wave per Wk row -> fully coalesced 1KB row reads. grid (4, B).
__global__ __launch_bounds__(256) void qk_kernel(
        const float* __restrict__ qbuf, const float* __restrict__ Wk,
        float* __restrict__ qk)
{
    const int b = blockIdx.y;
    const int tid = threadIdx.x;
    const int wave = tid >> 6, lane = tid & 63;
    __shared__ float qs[DIM];
    qs[tid] = qbuf[b*DIM + tid];
    __syncthreads();
    const float ascale = 0.17677669529663687f; // 32^-0.5
    const float4 qv = *(const float4*)&qs[lane*4];
    #pragma unroll 4
    for (int i = 0; i < 16; ++i) {
        const int c = blockIdx.x*64 + wave*16 + i;
        const float4 w = *(const float4*)&Wk[(size_t)c*INNER + lane*4];
        float part = w.x*qv.x + w.y*qv.y + w.z*qv.z + w.w*qv.w;
        part += __shfl_xor(part, 1);
        part += __shfl_xor(part, 2);
        part += __shfl_xor(part, 4);
        if ((lane & 7) == 0)
            qk[(b*HEADS + (lane >> 3))*DIM + c] = part * ascale;
    }
}

// ---------------------------------------------------------------------------
// K2: dots[b,h,n] = sum_c x[b,n,c] * qk[b,h,c]
__global__ __launch_bounds__(256) void dots_kernel(
        const float* __restrict__ x, const float* __restrict__ qk,
        float* __restrict__ dots)
{
    const int b = blockIdx.y;
    const int n0 = blockIdx.x * 32;
    const int tid = threadIdx.x;
    __shared__ float xs[32][260];
    __shared__ float qs[HEADS][260];
    const float4* xg = (const float4*)(x + (size_t)b*NTOK*DIM + (size_t)n0*DIM);
    #pragma unroll
    for (int i = 0; i < 8; ++i) {
        int flat = tid + 256*i;
        int r = flat >> 6, c4 = flat & 63;
        *(float4*)&xs[r][c4*4] = xg[flat];
    }
    const float4* qg = (const float4*)(qk + (size_t)b*HEADS*DIM);
    #pragma unroll
    for (int i = 0; i < 2; ++i) {
        int flat = tid + 256*i;
        int h = flat >> 6, c4 = flat & 63;
        *(float4*)&qs[h][c4*4] = qg[flat];
    }
    __syncthreads();
    const int tok = tid >> 3, h = tid & 7;
    float acc = 0.f;
    #pragma unroll 8
    for (int i = 0; i < 64; ++i) {
        float4 xv = *(const float4*)&xs[tok][i*4];
        float4 qv = *(const float4*)&qs[h][i*4];
        acc += xv.x*qv.x + xv.y*qv.y + xv.z*qv.z + xv.w*qv.w;
    }
    dots[((size_t)(b*HEADS + h))*NTOK + n0 + tok] = acc;
}

// ---------------------------------------------------------------------------
// K3: softmax over last dim (4096), in place.
__global__ __launch_bounds__(256) void softmax_kernel(float* __restrict__ dots)
{
    float* p = dots + (size_t)blockIdx.x * NTOK;
    const int tid = threadIdx.x;
    float v[16];
    float mx = -3.4e38f;
    #pragma unroll
    for (int i = 0; i < 16; ++i) { v[i] = p[tid + 256*i]; mx = fmaxf(mx, v[i]); }
    #pragma unroll
    for (int o = 32; o > 0; o >>= 1) mx = fmaxf(mx, __shfl_xor(mx, o));
    __shared__ float red[4];
    const int wave = tid >> 6;
    if ((tid & 63) == 0) red[wave] = mx;
    __syncthreads();
    mx = fmaxf(fmaxf(red[0], red[1]), fmaxf(red[2], red[3]));
    float s = 0.f;
    #pragma unroll
    for (int i = 0; i < 16; ++i) { v[i] = __expf(v[i] - mx); s += v[i]; }
    #pragma unroll
    for (int o = 32; o > 0; o >>= 1) s += __shfl_xor(s, o);
    __syncthreads();
    if ((tid & 63) == 0) red[wave] = s;
    __syncthreads();
    s = red[0] + red[1] + red[2] + red[3];
    const float inv = 1.f / s;
    #pragma unroll
    for (int i = 0; i < 16; ++i) p[tid + 256*i] = v[i] * inv;
}

// ---------------------------------------------------------------------------
// K5: xa[b,h,c] += sum_n attn[b,h,n] * x[b,n,c]
__global__ __launch_bounds__(256) void xa_kernel(
        const float* __restrict__ x, const float* __restrict__ attn,
        float* __restrict__ xa)
{
    const int b = blockIdx.y;
    const int n0 = blockIdx.x * (NTOK/8);
    const int tid = threadIdx.x;
    __shared__ float as[HEADS][NTOK/8];
    const float* ag = attn + (size_t)b*HEADS*NTOK;
    #pragma unroll
    for (int i = 0; i < 16; ++i) {
        int flat = tid + 256*i;
        int h = flat >> 9, n = flat & 511;
        as[h][n] = ag[(size_t)h*NTOK + n0 + n];
    }
    __syncthreads();
    float acc[HEADS];
    #pragma unroll
    for (int h = 0; h < HEADS; ++h) acc[h] = 0.f;
    const float* xg = x + (size_t)b*NTOK*DIM + (size_t)n0*DIM + tid;
    for (int n = 0; n < NTOK/8; ++n) {
        float xv = xg[(size_t)n*DIM];
        #pragma unroll
        for (int h = 0; h < HEADS; ++h) acc[h] += as[h][n] * xv;
    }
    #pragma unroll
    for (int h = 0; h < HEADS; ++h)
        atomicAdd(&xa[(b*HEADS + h)*DIM + tid], acc[h]);
}

// ---------------------------------------------------------------------------
// K6: vo = xa @ Wv per head, out = vo@Wo + bo, x[b,idx] += out
__global__ __launch_bounds__(256) void attn_out_kernel(
        const float* __restrict__ xa, const float* __restrict__ Wv,
        const float* __restrict__ Wo, const float* __restrict__ bo,
        const int* __restrict__ pidx, const int* __restrict__ scale,
        float* __restrict__ x)
{
    const int b = blockIdx.x;
    const int tid = threadIdx.x;
    __shared__ float xs[HEADS*DIM];
    __shared__ float vs[INNER];
    #pragma unroll
    for (int i = 0; i < 8; ++i) xs[tid + 256*i] = xa[b*HEADS*DIM + tid + 256*i];
    __syncthreads();
    const int h = tid >> 5;
    float acc = 0.f;
    #pragma unroll 4
    for (int c = 0; c < DIM; ++c) acc += xs[h*DIM + c] * Wv[c*INNER + tid];
    vs[tid] = acc;
    __syncthreads();
    float o = bo[tid];
    #pragma unroll 4
    for (int i = 0; i < INNER; ++i) o += vs[i] * Wo[i*DIM + tid];
    const int idx = pidx[b*2 + 0] * scale[1] + pidx[b*2 + 1];
    x[(size_t)b*NTOK*DIM + (size_t)idx*DIM + tid] += o;
}

// ---------------------------------------------------------------------------
// K7: fused FFN, fp16 MFMA, 64-token tile, 4 waves, 2-deep register pipeline.
__global__ __launch_bounds__(256, 2) void ffn_mfma(
        float* __restrict__ x,
        const float* __restrict__ g, const float* __restrict__ bvec,
        const _Float16* __restrict__ W1F, const float* __restrict__ b1,
        const _Float16* __restrict__ W2F, const float* __restrict__ b2)
{
    __shared__ _Float16 xs[64*256];   // [t][k], swizzled
    __shared__ _Float16 hsT[64*256];  // [t][chunk-c], swizzled
    const int tid = threadIdx.x;
    const size_t row0 = (size_t)blockIdx.x * 64;

    // ---- phase 1: LN (fp32) -> fp16 -> xs
    {
        const int r = tid >> 2, p = tid & 3;
        const float4* xg = (const float4*)(x + (row0 + r)*DIM) + p*16;
        float4 v[16];
        float s = 0.f, s2 = 0.f;
        #pragma unroll
        for (int i = 0; i < 16; ++i) {
            v[i] = xg[i];
            s  += v[i].x + v[i].y + v[i].z + v[i].w;
            s2 += v[i].x*v[i].x + v[i].y*v[i].y + v[i].z*v[i].z + v[i].w*v[i].w;
        }
        s  += __shfl_xor(s, 1);  s  += __shfl_xor(s, 2);
        s2 += __shfl_xor(s2, 1); s2 += __shfl_xor(s2, 2);
        const float mean = s * (1.f/DIM);
        const float rstd = rsqrtf(s2*(1.f/DIM) - mean*mean + EPS);
        #pragma unroll
        for (int q = 0; q < 8; ++q) {
            const int c8 = p*64 + q*8;
            const float4 ga = *(const float4*)&g[c8];
            const float4 gb = *(const float4*)&g[c8+4];
            const float4 ba = *(const float4*)&bvec[c8];
            const float4 bb = *(const float4*)&bvec[c8+4];
            const float4 a = v[2*q], d = v[2*q+1];
            half8 hh;
            hh[0] = (_Float16)((a.x-mean)*rstd*ga.x + ba.x);
            hh[1] = (_Float16)((a.y-mean)*rstd*ga.y + ba.y);
            hh[2] = (_Float16)((a.z-mean)*rstd*ga.z + ba.z);
            hh[3] = (_Float16)((a.w-mean)*rstd*ga.w + ba.w);
            hh[4] = (_Float16)((d.x-mean)*rstd*gb.x + bb.x);
            hh[5] = (_Float16)((d.y-mean)*rstd*gb.y + bb.y);
            hh[6] = (_Float16)((d.z-mean)*rstd*gb.z + bb.z);
            hh[7] = (_Float16)((d.w-mean)*rstd*gb.w + bb.w);
            int byte = r*512 + c8*2;
            byte ^= (r & 7) << 4;
            *(half8*)((char*)xs + byte) = hh;
        }
    }
    __syncthreads();

    const int wave = tid >> 6, lane = tid & 63;
    const int lr = lane & 15, lhi = lane >> 4;

    f32x4 acc2[4][4];
    #pragma unroll
    for (int m = 0; m < 4; ++m)
        #pragma unroll
        for (int n = 0; n < 4; ++n) acc2[m][n] = (f32x4)0.f;

    half8 aA[4], aB[4], bA[4], bB[4];

    for (int cc = 0; cc < 4; ++cc) {
        auto ldA1 = [&](int ks, half8* a) {
            #pragma unroll
            for (int m = 0; m < 4; ++m)
                a[m] = *((const half8*)W1F +
                         (size_t)((cc*16 + wave*4 + m)*8 + ks)*64 + lane);
        };
        auto ldA2 = [&](int ks, half8* a) {
            #pragma unroll
            for (int m = 0; m < 4; ++m)
                a[m] = *((const half8*)W2F +
                         (size_t)((wave*4 + m)*32 + cc*8 + ks)*64 + lane);
        };
        auto ldB = [&](const _Float16* src, int ks, half8* bf) {
            #pragma unroll
            for (int n = 0; n < 4; ++n) {
                int byte = (n*16 + lr)*512 + (ks*32 + lhi*8)*2;
                byte ^= (lr & 7) << 4;
                bf[n] = *(const half8*)((const char*)src + byte);
            }
        };
        auto mm = [&](f32x4 (&acc)[4][4], half8* a, half8* bf) {
            #pragma unroll
            for (int m = 0; m < 4; ++m)
                #pragma unroll
                for (int n = 0; n < 4; ++n)
                    acc[m][n] = __builtin_amdgcn_mfma_f32_16x16x32_f16(
                        a[m], bf[n], acc[m][n], 0, 0, 0);
        };

        // ---- GEMM1: acc1 = W1^T-slice x X^T, software-pipelined
        f32x4 acc1[4][4];
        #pragma unroll
        for (int m = 0; m < 4; ++m)
            #pragma unroll
            for (int n = 0; n < 4; ++n) acc1[m][n] = (f32x4)0.f;
        ldA1(0, aA); ldB(xs, 0, bA);
        #pragma unroll
        for (int kp = 0; kp < 4; ++kp) {
            ldA1(2*kp+1, aB); ldB(xs, 2*kp+1, bB);
            mm(acc1, aA, bA);
            if (kp < 3) { ldA1(2*kp+2, aA); ldB(xs, 2*kp+2, bA); }
            mm(acc1, aB, bB);
        }
        // prefetch GEMM2's first A (global, independent of barriers) + b1
        f32x4 b1r[4];
        #pragma unroll
        for (int m = 0; m < 4; ++m)
            b1r[m] = *(const f32x4*)(b1 + cc*256 + wave*64 + m*16 + lhi*4);
        ldA2(0, aA);
        __syncthreads();   // prev chunk's GEMM2 done reading hsT
        // ---- bias + GELU + fp16 -> hsT
        #pragma unroll
        for (int m = 0; m < 4; ++m) {
            #pragma unroll
            for (int n = 0; n < 4; ++n) {
                const int t = n*16 + lr;
                half4v hv;
                hv[0] = (_Float16)gelu_fast(acc1[m][n][0] + b1r[m][0]);
                hv[1] = (_Float16)gelu_fast(acc1[m][n][1] + b1r[m][1]);
                hv[2] = (_Float16)gelu_fast(acc1[m][n][2] + b1r[m][2]);
                hv[3] = (_Float16)gelu_fast(acc1[m][n][3] + b1r[m][3]);
                int byte = t*512 + (wave*64 + m*16 + lhi*4)*2;
                byte ^= (t & 7) << 4;
                *(half4v*)((char*)hsT + byte) = hv;
            }
        }
        __syncthreads();   // hsT ready
        // ---- GEMM2: acc2 += W2^T-slice x H^T, software-pipelined
        ldB(hsT, 0, bA);
        #pragma unroll
        for (int kp = 0; kp < 4; ++kp) {
            ldA2(2*kp+1, aB); ldB(hsT, 2*kp+1, bB);
            mm(acc2, aA, bA);
            if (kp < 3) { ldA2(2*kp+2, aA); ldB(hsT, 2*kp+2, bA); }
            mm(acc2, aB, bB);
        }
    }
    // ---- epilogue: Y^T + b2 + residual -> x
    #pragma unroll
    for (int m = 0; m < 4; ++m) {
        const int c0 = wave*64 + m*16 + lhi*4;
        const f32x4 b2v = *(const f32x4*)(b2 + c0);
        #pragma unroll
        for (int n = 0; n < 4; ++n) {
            const int t = n*16 + lr;
            float* xp = x + (row0 + t)*DIM + c0;
            float4 r = *(const float4*)xp;
            r.x += acc2[m][n][0] + b2v[0];
            r.y += acc2[m][n][1] + b2v[1];
            r.z += acc2[m][n][2] + b2v[2];
            r.w += acc2[m][n][3] + b2v[3];
            *(float4*)xp = r;
        }
    }
}

// ---------------------------------------------------------------------------
// K8: final layernorm
__global__ __launch_bounds__(256) void final_ln_kernel(
        const float* __restrict__ x, const float* __restrict__ g,
        const float* __restrict__ bvec, float* __restrict__ out)
{
    const int tid = threadIdx.x;
    const size_t row = (size_t)blockIdx.x*32 + (tid >> 3);
    const int p = tid & 7;
    const float4* xr = (const float4*)(x + row*DIM);
    float4 v[8];
    float s = 0.f, s2 = 0.f;
    #pragma unroll
    for (int i = 0; i < 8; ++i) {
        v[i] = xr[p + 8*i];
        s  += v[i].x + v[i].y + v[i].z + v[i].w;
        s2 += v[i].x*v[i].x + v[i].y*v[i].y + v[i].z*v[i].z + v[i].w*v[i].w;
    }
    #pragma unroll
    for (int o = 1; o < 8; o <<= 1) { s += __shfl_xor(s, o); s2 += __shfl_xor(s2, o); }
    const float mean = s * (1.f/DIM);
    const float rstd = rsqrtf(s2*(1.f/DIM) - mean*mean + EPS);
    float4* og = (float4*)(out + row*DIM);
    #pragma unroll
    for (int i = 0; i < 8; ++i) {
        const int c4 = (p + 8*i)*4;
        const float4 gg = *(const float4*)&g[c4];
        const float4 bb = *(const float4*)&bvec[c4];
        float4 o_;
        o_.x = (v[i].x - mean)*rstd*gg.x + bb.x;
        o_.y = (v[i].y - mean)*rstd*gg.y + bb.y;
        o_.z = (v[i].z - mean)*rstd*gg.z + bb.z;
        o_.w = (v[i].w - mean)*rstd*gg.w + bb.w;
        og[p + 8*i] = o_;
    }
}

// ---------------------------------------------------------------------------
extern "C" void kernel_launch(void* const* d_in, const int* in_sizes, int n_in,
                              void* d_out, int out_size, void* d_ws, size_t ws_size,
                              hipStream_t stream)
{
    const float* x_in  = (const float*)d_in[0];
    const int*   pidx  = (const int*)d_in[1];
    const int*   scale = (const int*)d_in[3];
    const float* Wq    = (const float*)d_in[4];
    const float* Wk    = (const float*)d_in[5];
    const float* Wv    = (const float*)d_in[6];
    const float* Wo    = (const float*)d_in[7];
    const float* bo    = (const float*)d_in[8];
    const float* ln_g  = (const float*)d_in[9];
    const float* ln_b  = (const float*)d_in[10];
    const float* W1    = (const float*)d_in[11];
    const float* b1    = (const float*)d_in[12];
    const float* W2    = (const float*)d_in[13];
    const float* b2    = (const float*)d_in[14];
    const float* lnf_g = (const float*)d_in[15];
    const float* lnf_b = (const float*)d_in[16];

    float* xbuf = (float*)d_out;                      // x lives in d_out
    float* qk   = (float*)d_ws;                       // B*H*DIM f32
    float* dots = qk + (size_t)B*HEADS*DIM;           // B*H*NTOK f32
    float* xa   = dots + (size_t)B*HEADS*NTOK;        // B*H*DIM f32
    float* qbuf = xa + (size_t)B*HEADS*DIM;           // B*DIM f32
    _Float16* W1F = (_Float16*)(qbuf + (size_t)B*DIM);   // DEPTH*DIM*MLPD f16
    _Float16* W2F = W1F + (size_t)DEPTH*DIM*MLPD;        // DEPTH*MLPD*DIM f16

    pack_w<<<dim3(MLPD/64, DIM/32, DEPTH), 256, 0, stream>>>(W1, W1F, DIM, MLPD);
    pack_w<<<dim3(DIM/64, MLPD/32, DEPTH), 256, 0, stream>>>(W2, W2F, MLPD, DIM);

    hipMemcpyAsync(xbuf, x_in, (size_t)B*NTOK*DIM*sizeof(float),
                   hipMemcpyDeviceToDevice, stream);

    for (int l = 0; l < DEPTH; ++l) {
        attn_prep<<<B, 256, 0, stream>>>(
            xbuf, pidx, scale, Wq + (size_t)l*DIM*INNER, qbuf);
        qk_kernel<<<dim3(4, B), 256, 0, stream>>>(
            qbuf, Wk + (size_t)l*DIM*INNER, qk);
        dots_kernel<<<dim3(NTOK/32, B), 256, 0, stream>>>(xbuf, qk, dots);
        softmax_kernel<<<B*HEADS, 256, 0, stream>>>(dots);
        hipMemsetAsync(xa, 0, (size_t)B*HEADS*DIM*sizeof(float), stream);
        xa_kernel<<<dim3(8, B), 256, 0, stream>>>(xbuf, dots, xa);
        attn_out_kernel<<<B, 256, 0, stream>>>(
            xa, Wv + (size_t)l*DIM*INNER, Wo + (size_t)l*INNER*DIM,
            bo + (size_t)l*DIM, pidx, scale, xbuf);
        ffn_mfma<<<(B*NTOK)/64, 256, 0, stream>>>(
            xbuf, ln_g + (size_t)l*DIM, ln_b + (size_t)l*DIM,
            W1F + (size_t)l*DIM*MLPD, b1 + (size_t)l*MLPD,
            W2F + (size_t)l*MLPD*DIM, b2 + (size_t)l*DIM);
    }
    final_ln_kernel<<<(B*NTOK)/32, 256, 0, stream>>>(xbuf, lnf_g, lnf_b, xbuf);
}